// Round 1
// baseline (128.893 us; speedup 1.0000x reference)
//
#include <hip/hip_runtime.h>

#define B_CONST 16
#define S_CONST 512
#define D_CONST 384

// Kernel 1: per-batch inclusive scan of durations.
// One block per batch, 512 threads (8 waves of 64).
__global__ void scan_kernel(const int* __restrict__ dur, int* __restrict__ csum,
                            int* __restrict__ lenArr, float* __restrict__ outLenF) {
    int b = blockIdx.x;
    int s = threadIdx.x;
    int v = dur[b * S_CONST + s];
    int lane = s & 63;
    int wave = s >> 6;
    int x = v;
    // wave-level inclusive scan (wave = 64 on CDNA)
    #pragma unroll
    for (int off = 1; off < 64; off <<= 1) {
        int y = __shfl_up(x, off, 64);
        if (lane >= off) x += y;
    }
    __shared__ int wsum[8];
    if (lane == 63) wsum[wave] = x;
    __syncthreads();
    if (s == 0) {
        int acc = 0;
        #pragma unroll
        for (int w = 0; w < 8; ++w) { int t = wsum[w]; wsum[w] = acc; acc += t; }
    }
    __syncthreads();
    x += wsum[wave];
    csum[b * S_CONST + s] = x;
    if (s == S_CONST - 1) {
        lenArr[b] = x;            // int copy for device use
        outLenF[b] = (float)x;    // harness reads flat buffer as float32
    }
}

// Kernel 2: one thread per output frame (b, j): binary-search csum for the
// source token (searchsorted side='right': smallest t with csum[t] > j).
// Stores the GLOBAL token index b*S + t, or -1 for the zero-padding region.
__global__ void idx_kernel(const int* __restrict__ csum, const int* __restrict__ lenArr,
                           int* __restrict__ gidx, int L) {
    int t = blockIdx.x * blockDim.x + threadIdx.x;
    if (t >= B_CONST * L) return;
    int b = t / L;
    int j = t - b * L;
    if (j >= lenArr[b]) { gidx[t] = -1; return; }
    const int* c = csum + b * S_CONST;
    int lo = 0, hi = S_CONST;
    while (lo < hi) {
        int mid = (lo + hi) >> 1;
        if (c[mid] <= j) lo = mid + 1; else hi = mid;
    }
    if (lo > S_CONST - 1) lo = S_CONST - 1;   // clamp (padding guard)
    gidx[t] = b * S_CONST + lo;
}

// Kernel 3: coalesced gather, one thread per float4 of output (D=384 -> 96 float4/row).
__global__ void gather_kernel(const float4* __restrict__ hidden4,
                              const int* __restrict__ gidx,
                              float4* __restrict__ out4, int total4) {
    int t = blockIdx.x * blockDim.x + threadIdx.x;
    if (t >= total4) return;
    const int K = D_CONST / 4;  // 96
    int row = t / K;            // compile-time-constant divide -> magic mul
    int k = t - row * K;
    int g = gidx[row];          // broadcast within the 96 threads of a row (L1 hit)
    float4 val;
    if (g < 0) {
        val = make_float4(0.f, 0.f, 0.f, 0.f);
    } else {
        val = hidden4[(size_t)g * K + k];
    }
    out4[t] = val;
}

extern "C" void kernel_launch(void* const* d_in, const int* in_sizes, int n_in,
                              void* d_out, int out_size, void* d_ws, size_t ws_size,
                              hipStream_t stream) {
    const int* durations = (const int*)d_in[1];
    const float* hidden  = (const float*)d_in[0];
    float* out = (float*)d_out;

    // out_size = B*L*D + B  (output 0 flat + lengths)
    int L = (out_size - B_CONST) / (B_CONST * D_CONST);

    // workspace layout
    int* csum   = (int*)d_ws;                    // B*S
    int* lenArr = csum + B_CONST * S_CONST;      // B
    int* gidx   = lenArr + B_CONST;              // B*L

    float* outLenF = out + (size_t)B_CONST * L * D_CONST;

    scan_kernel<<<B_CONST, S_CONST, 0, stream>>>(durations, csum, lenArr, outLenF);

    int nIdx = B_CONST * L;
    idx_kernel<<<(nIdx + 255) / 256, 256, 0, stream>>>(csum, lenArr, gidx, L);

    int total4 = B_CONST * L * (D_CONST / 4);
    gather_kernel<<<(total4 + 255) / 256, 256, 0, stream>>>(
        (const float4*)hidden, gidx, (float4*)out, total4);
}

// Round 2
// 118.818 us; speedup vs baseline: 1.0848x; 1.0848x over previous
//
#include <hip/hip_runtime.h>

#define NB 16      // batch
#define NS 512     // tokens
#define ND 384     // hidden dim
#define K4 (ND/4)  // float4s per row = 96
#define ROWS 16    // output rows per block
#define NT 256     // threads per block (4 waves)

// One fused kernel. Each block: (batch b, chunk of ROWS output rows).
//  1. Load the batch's 512 durations (2 KB, L2-hot), inclusive-scan into LDS.
//  2. 16 threads binary-search the LDS csum for their row's source token.
//  3. All 256 threads gather/store ROWS*96 float4s, coalesced.
// Chunk-0 blocks also write out_lengths[b] (as float — harness reads flat f32).
__global__ __launch_bounds__(NT) void length_regulator_fused(
    const float4* __restrict__ hidden4,   // [B*S*96]
    const int*    __restrict__ dur,       // [B*S]
    float4*       __restrict__ out4,      // [B*L*96]
    float*        __restrict__ outLenF,   // [B], after out4 region
    int L)
{
    const int t = threadIdx.x;
    const int b = blockIdx.y;
    const int chunk = blockIdx.x;
    const int j0 = chunk * ROWS;

    __shared__ int csum[NS];
    __shared__ int wsum[NT / 64];
    __shared__ int rowTok[ROWS];

    // ---- scan: 2 durations per thread ----
    int2 d2 = ((const int2*)(dur + b * NS))[t];   // elements 2t, 2t+1
    int local = d2.x + d2.y;
    int lane = t & 63, wave = t >> 6;
    int x = local;
    #pragma unroll
    for (int off = 1; off < 64; off <<= 1) {
        int y = __shfl_up(x, off, 64);
        if (lane >= off) x += y;
    }
    if (lane == 63) wsum[wave] = x;
    __syncthreads();
    if (t == 0) {
        int acc = 0;
        #pragma unroll
        for (int w = 0; w < NT / 64; ++w) { int tmp = wsum[w]; wsum[w] = acc; acc += tmp; }
    }
    __syncthreads();
    int excl = wsum[wave] + x - local;            // exclusive prefix before element 2t
    csum[2 * t]     = excl + d2.x;
    csum[2 * t + 1] = excl + local;
    __syncthreads();

    const int total = csum[NS - 1];               // this batch's expanded length

    if (chunk == 0 && t == 0) outLenF[b] = (float)total;

    // ---- per-row source token via binary search (searchsorted side='right') ----
    if (t < ROWS) {
        int j = j0 + t;
        int g = -1;                               // -1 => zero padding
        if (j < L && j < total) {
            int lo = 0, hi = NS;
            while (lo < hi) {
                int mid = (lo + hi) >> 1;
                if (csum[mid] <= j) lo = mid + 1; else hi = mid;
            }
            if (lo > NS - 1) lo = NS - 1;
            g = lo;
        }
        rowTok[t] = g;
    }
    __syncthreads();

    // ---- gather / store: ROWS*96 = 1536 float4s, 6 per thread, coalesced ----
    const size_t outBase = ((size_t)b * L + j0) * K4;
    #pragma unroll
    for (int i = t; i < ROWS * K4; i += NT) {
        int r = i / K4;                           // compile-time const -> magic mul
        int k = i - r * K4;
        int j = j0 + r;
        if (j >= L) break;                        // tail chunk guard (r monotonic in i)
        int g = rowTok[r];
        float4 v;
        if (g < 0) v = make_float4(0.f, 0.f, 0.f, 0.f);
        else       v = hidden4[(size_t)(b * NS + g) * K4 + k];
        out4[outBase + i] = v;
    }
}

extern "C" void kernel_launch(void* const* d_in, const int* in_sizes, int n_in,
                              void* d_out, int out_size, void* d_ws, size_t ws_size,
                              hipStream_t stream) {
    const float* hidden   = (const float*)d_in[0];
    const int*   durations = (const int*)d_in[1];
    float* out = (float*)d_out;

    // out_size = B*L*D + B
    int L = (out_size - NB) / (NB * ND);
    float* outLenF = out + (size_t)NB * L * ND;

    dim3 grid((L + ROWS - 1) / ROWS, NB);
    length_regulator_fused<<<grid, NT, 0, stream>>>(
        (const float4*)hidden, durations, (float4*)out, outLenF, L);
}